// Round 3
// baseline (797.873 us; speedup 1.0000x reference)
//
#include <hip/hip_runtime.h>
#include <stdint.h>

typedef unsigned int u32;
typedef unsigned long long u64;
typedef unsigned short u16;
typedef unsigned char u8;

#define NPTS 8192
#define GRIDW 64
#define NCELLS 4096
#define CAP 32
#define SEG 1024
#define NSEG 8
#define KMAX 8
#define NBLK 256

// Device-scope grid barrier. 256 blocks x 1024 thr, 24.6KB LDS -> exactly one
// block per CU, all co-resident, so spin-wait cannot deadlock. Bounded spin as
// a safety valve (wrong-result instead of GPU hang).
__device__ __forceinline__ void grid_barrier(u32* cnt, u32* gen) {
  __threadfence();
  __syncthreads();
  if (threadIdx.x == 0) {
    u32 g = __hip_atomic_load(gen, __ATOMIC_RELAXED, __HIP_MEMORY_SCOPE_AGENT);
    u32 a = __hip_atomic_fetch_add(cnt, 1u, __ATOMIC_ACQ_REL, __HIP_MEMORY_SCOPE_AGENT);
    if (a == NBLK - 1) {
      __hip_atomic_store(cnt, 0u, __ATOMIC_RELAXED, __HIP_MEMORY_SCOPE_AGENT);
      __hip_atomic_fetch_add(gen, 1u, __ATOMIC_RELEASE, __HIP_MEMORY_SCOPE_AGENT);
    } else {
      long sp = 0;
      while (__hip_atomic_load(gen, __ATOMIC_ACQUIRE, __HIP_MEMORY_SCOPE_AGENT) == g) {
        __builtin_amdgcn_s_sleep(1);
        if (++sp > (4L << 20)) break;  // ~0.1 s safety valve
      }
    }
  }
  __syncthreads();
  __threadfence();
}

__global__ __launch_bounds__(1024, 1) void k_fused(
    const float* __restrict__ coords, const float* __restrict__ scores,
    float* __restrict__ out,
    u64* __restrict__ key, u32* __restrict__ cell_of, u32* __restrict__ cell_count,
    u32* __restrict__ cell_start, u16* __restrict__ cell_pts,
    u32* __restrict__ sorted_id, float* __restrict__ sx, float* __restrict__ sy,
    float* __restrict__ ss, u16* __restrict__ scell, u32* __restrict__ rank,
    u32* __restrict__ nbr_cnt, u16* __restrict__ nbr,
    u32* __restrict__ cell_cursor, u32* __restrict__ bar) {
  __shared__ u8 smem[8192 + 2 * SEG * KMAX + 64];  // keep | in-seg lists | flags
  int B = blockIdx.x, t = threadIdx.x;
  int gid = B * 1024 + t;
  u32* bcnt = bar;
  u32* bgen = bar + 1;

  // ---- phase 1: priority keys, cell ids, cell histogram -------------------
  if (gid < NPTS) {
    int i = gid;
    float x = coords[2 * i], y = coords[2 * i + 1];
    // scores in [0,1): positive floats -> bit pattern order-preserving;
    // tie-break smaller index first (stable argsort(-s)).
    u32 sb = __float_as_uint(scores[i]);
    key[i] = ((u64)sb << 32) | (u64)(0xFFFFFFFFu - (u32)i);
    int cx = (int)(x * 0.125f); cx = cx < 0 ? 0 : (cx > 63 ? 63 : cx);
    int cy = (int)(y * 0.125f); cy = cy < 0 ? 0 : (cy > 63 ? 63 : cy);
    u32 c = (u32)(cy * GRIDW + cx);
    cell_of[i] = c;
    atomicAdd(&cell_count[c], 1u);
  }
  grid_barrier(bcnt, bgen);

  // ---- phase 2: rank (blocks 0..127) || cell-count scan (block 255) -------
  if (gid < NPTS * 16) {
    int p = gid & (NPTS - 1);
    int c = gid >> 13;  // 0..15, wave-uniform
    u64 kp = key[p];
    const u64* base = key + c * 512;
    u32 cv = 0;
#pragma unroll 8
    for (int i = 0; i < 512; ++i) cv += (base[i] > kp) ? 1u : 0u;
    if (cv) atomicAdd(&rank[p], cv);
  }
  if (B == NBLK - 1) {
    u32* part = (u32*)smem;
    u32 v0 = cell_count[4 * t], v1 = cell_count[4 * t + 1];
    u32 v2 = cell_count[4 * t + 2], v3 = cell_count[4 * t + 3];
    u32 sum = v0 + v1 + v2 + v3;
    part[t] = sum;
    __syncthreads();
    for (int off = 1; off < 1024; off <<= 1) {
      u32 x = (t >= off) ? part[t - off] : 0u;
      __syncthreads();
      part[t] += x;
      __syncthreads();
    }
    u32 excl = part[t] - sum;
    cell_start[4 * t] = excl;
    cell_start[4 * t + 1] = excl + v0;
    cell_start[4 * t + 2] = excl + v0 + v1;
    cell_start[4 * t + 3] = excl + v0 + v1 + v2;
  }
  grid_barrier(bcnt, bgen);

  // ---- phase 3: scatter into rank space -----------------------------------
  if (gid < NPTS) {
    int i = gid;
    u32 c = cell_of[i];
    u32 r = rank[i];
    u32 sl = atomicAdd(&cell_cursor[c], 1u);
    cell_pts[cell_start[c] + sl] = (u16)r;
    sorted_id[r] = (u32)i;
    sx[r] = coords[2 * i];   // bitwise copies keep arithmetic exact
    sy[r] = coords[2 * i + 1];
    ss[r] = scores[i];
    scell[r] = (u16)c;
  }
  grid_barrier(bcnt, bgen);

  // ---- phase 4: higher-priority in-radius neighbor lists (9 x 8192 items) -
  if (gid < 9 * NPTS) {
    int kk = gid >> 13;  // 0..8, which of the 3x3 cells
    int r = gid & (NPTS - 1);
    int dxc = kk % 3 - 1, dyc = kk / 3 - 1;
    float x = sx[r], y = sy[r];
    int c = scell[r];
    int cx = (c & 63) + dxc, cy = (c >> 6) + dyc;
    if (cx >= 0 && cx <= 63 && cy >= 0 && cy <= 63) {
      int cc = cy * GRIDW + cx;
      u32 s0 = cell_start[cc], n = cell_count[cc];
      for (u32 p2 = 0; p2 < n; ++p2) {
        u32 q = cell_pts[s0 + p2];
        if ((int)q < r) {  // strictly higher priority
          // mirror reference arithmetic: sub, mul, mul, add, sqrt, cmp
          float ddx = __fsub_rn(x, sx[q]);
          float ddy = __fsub_rn(y, sy[q]);
          float d2 = __fadd_rn(__fmul_rn(ddx, ddx), __fmul_rn(ddy, ddy));
          if (__fsqrt_rn(d2) < 8.0f) {
            u32 sl = atomicAdd(&nbr_cnt[r], 1u);
            if (sl < CAP) nbr[(size_t)sl * NPTS + r] = (u16)q;
          }
        }
      }
    }
  }
  grid_barrier(bcnt, bgen);

  if (B != 0) return;

  // ---- phase 5: segmented Gauss-Seidel fixpoint (block 0 only) ------------
  // Round 0 per segment: one coalesced global pass caches in-seg neighbor
  // ranks (expected ~0.8/point) in LDS; prefix-kept => final 0; no in-seg
  // deps => final 1. Rounds >=1 are LDS-only Jacobi over active threads.
  u8* keep = smem;
  u16* ins = (u16*)(smem + 8192);
  int* slot = (int*)(smem + 8192 + 2 * SEG * KMAX);

  for (int s = 0; s < NSEG; ++s) {
    int segbase = s << 10;
    int p = segbase + t;
    u32 cnt = nbr_cnt[p]; if (cnt > CAP) cnt = CAP;
    const u16* row = nbr + p;  // entry n at row[n*NPTS], coalesced over t
    u32 kin = 0;
    bool supPrefix = false;
    for (u32 n = 0; n < cnt; ++n) {
      u32 q = row[(size_t)n * NPTS];
      if (q < (u32)segbase) {
        if (keep[q]) { supPrefix = true; break; }  // prefix is final
      } else {
        if (kin < KMAX) ins[t * KMAX + kin] = (u16)q;
        kin++;
      }
    }
    bool fallback = (kin > KMAX);  // rare: rescan global row each round
    bool active = !supPrefix && (kin > 0);
    keep[p] = supPrefix ? (u8)0 : (u8)1;
    if (t < 4) slot[t] = 0;
    __syncthreads();

    // 4-slot rotating changed-flag: 1 barrier/round. slot[r&3] written in
    // round r, read after round r's barrier, reset at round r+2 (all readers
    // are past round r+1's barrier by then).
    for (int r = 1; r <= SEG + 2; ++r) {
      if (t == 0) slot[(r + 2) & 3] = 0;
      bool flip = false;
      if (active) {
        bool alive = true;
        if (!fallback) {
          for (u32 n = 0; n < kin; ++n)
            if (keep[ins[t * KMAX + n]]) { alive = false; break; }
        } else {
          for (u32 n = 0; n < cnt; ++n) {
            u32 q = row[(size_t)n * NPTS];
            if (q >= (u32)segbase && keep[q]) { alive = false; break; }
          }
        }
        u8 a = alive ? (u8)1 : (u8)0;
        if (keep[p] != a) { keep[p] = a; flip = true; }
      }
      if (flip) slot[r & 3] = 1;
      __syncthreads();
      if (slot[r & 3] == 0) break;  // no flips in a full Jacobi round: fixpoint
    }
  }

  // ---- epilogue: keep mask (original order) + suppressed scores (rank order)
  for (int k2 = t; k2 < NPTS; k2 += 1024) {
    u8 kp = keep[k2];
    out[sorted_id[k2]] = kp ? 1.0f : 0.0f;
    out[NPTS + k2] = kp ? ss[k2] : 0.0f;
  }
}

// ---------------------------------------------------------------------------
extern "C" void kernel_launch(void* const* d_in, const int* in_sizes, int n_in,
                              void* d_out, int out_size, void* d_ws, size_t ws_size,
                              hipStream_t stream) {
  const float* coords = (const float*)d_in[0];  // [N,2]
  const float* scores = (const float*)d_in[1];  // [N]
  float* out = (float*)d_out;                   // [N keep | N suppressed scores]

  char* ws = (char*)d_ws;
  size_t off = 0;
  u64* key        = (u64*)(ws + off); off += (size_t)NPTS * 8;        // 64K
  u16* nbr        = (u16*)(ws + off); off += (size_t)CAP * NPTS * 2;  // 512K
  u32* cell_of    = (u32*)(ws + off); off += (size_t)NPTS * 4;        // 32K
  u32* cell_start = (u32*)(ws + off); off += (size_t)NCELLS * 4;      // 16K
  u16* cell_pts   = (u16*)(ws + off); off += (size_t)NPTS * 2;        // 16K
  u32* sorted_id  = (u32*)(ws + off); off += (size_t)NPTS * 4;        // 32K
  float* sx       = (float*)(ws + off); off += (size_t)NPTS * 4;      // 32K
  float* sy       = (float*)(ws + off); off += (size_t)NPTS * 4;      // 32K
  float* ss       = (float*)(ws + off); off += (size_t)NPTS * 4;      // 32K
  u16* scell      = (u16*)(ws + off); off += (size_t)NPTS * 2;        // 16K
  // zeroed region (single memset): counters + cursors + rank + nbr_cnt + bar
  char* zbase = ws + off;
  u32* cell_count  = (u32*)(ws + off); off += (size_t)NCELLS * 4;     // 16K
  u32* cell_cursor = (u32*)(ws + off); off += (size_t)NCELLS * 4;     // 16K
  u32* rank        = (u32*)(ws + off); off += (size_t)NPTS * 4;       // 32K
  u32* nbr_cnt     = (u32*)(ws + off); off += (size_t)NPTS * 4;       // 32K
  u32* bar         = (u32*)(ws + off); off += 256;                    // barrier state
  size_t zbytes = (size_t)NCELLS * 8 + (size_t)NPTS * 8 + 256;

  hipMemsetAsync(zbase, 0, zbytes, stream);
  k_fused<<<NBLK, 1024, 0, stream>>>(coords, scores, out, key, cell_of,
                                     cell_count, cell_start, cell_pts,
                                     sorted_id, sx, sy, ss, scell, rank,
                                     nbr_cnt, nbr, cell_cursor, bar);
}

// Round 4
// 213.951 us; speedup vs baseline: 3.7292x; 3.7292x over previous
//
#include <hip/hip_runtime.h>
#include <stdint.h>

typedef unsigned int u32;
typedef unsigned long long u64;
typedef unsigned short u16;
typedef unsigned char u8;

#define NPTS 8192
#define CAP 32
#define KMAX 8
#define SEG 1024
#define NSEG 8

// ---------------------------------------------------------------------------
// A: rank by counting + scatter into rank space. 256 blocks x 256 threads.
// Each block caches all 8192 score-bit keys in LDS (32 KB), then each thread
// owns 2 points x 1/16 key-slice: b128 LDS reads broadcast across the 16
// lanes sharing a slice (2-way bank aliasing only = free). Rank is exact:
// rank[p] = #{q: score_q > score_p or (==, q < p)} (stable argsort(-s)).
// Also zeroes nbr_cnt (block 0) -- no memset node needed.
// ---------------------------------------------------------------------------
__global__ __launch_bounds__(256) void k_rank(const float* __restrict__ coords,
                                              const float* __restrict__ scores,
                                              u32* __restrict__ sorted_id,
                                              float* __restrict__ sx,
                                              float* __restrict__ sy,
                                              float* __restrict__ ss,
                                              u32* __restrict__ nbr_cnt) {
  __shared__ u32 skey[NPTS];
  int t = threadIdx.x, B = blockIdx.x;
  for (int k = t; k < NPTS; k += 256) skey[k] = __float_as_uint(scores[k]);
  if (B == 0) {
    for (int k = t; k < NPTS; k += 256) nbr_cnt[k] = 0;
  }
  __syncthreads();

  int s = t & 15;   // slice 0..15, 512 keys each (consecutive lanes)
  int g = t >> 4;   // point group 0..15, 2 points each
  int p0 = B * 32 + g * 2;
  int p1 = p0 + 1;
  u32 kp0 = skey[p0];
  u32 kp1 = skey[p1];
  const uint4* k4 = (const uint4*)skey;
  int b4 = s << 7;  // slice base in uint4 units
  u32 c0 = 0, c1 = 0;
  for (int j = 0; j < 128; ++j) {
    int jj = (j + s) & 127;  // rotate: slices hit distinct bank groups
    uint4 kv = k4[b4 + jj];
    int q = (s << 9) + (jj << 2);
    c0 += (kv.x > kp0 || (kv.x == kp0 && q + 0 < p0)) ? 1u : 0u;
    c0 += (kv.y > kp0 || (kv.y == kp0 && q + 1 < p0)) ? 1u : 0u;
    c0 += (kv.z > kp0 || (kv.z == kp0 && q + 2 < p0)) ? 1u : 0u;
    c0 += (kv.w > kp0 || (kv.w == kp0 && q + 3 < p0)) ? 1u : 0u;
    c1 += (kv.x > kp1 || (kv.x == kp1 && q + 0 < p1)) ? 1u : 0u;
    c1 += (kv.y > kp1 || (kv.y == kp1 && q + 1 < p1)) ? 1u : 0u;
    c1 += (kv.z > kp1 || (kv.z == kp1 && q + 2 < p1)) ? 1u : 0u;
    c1 += (kv.w > kp1 || (kv.w == kp1 && q + 3 < p1)) ? 1u : 0u;
  }
  // butterfly sum over the 16 slices (lanes s..s^15 within one wave)
  c0 += __shfl_xor(c0, 1); c1 += __shfl_xor(c1, 1);
  c0 += __shfl_xor(c0, 2); c1 += __shfl_xor(c1, 2);
  c0 += __shfl_xor(c0, 4); c1 += __shfl_xor(c1, 4);
  c0 += __shfl_xor(c0, 8); c1 += __shfl_xor(c1, 8);
  if (s == 0) {
    sorted_id[c0] = (u32)p0;
    sx[c0] = coords[2 * p0];      // bitwise copies keep arithmetic exact
    sy[c0] = coords[2 * p0 + 1];
    ss[c0] = scores[p0];
    sorted_id[c1] = (u32)p1;
    sx[c1] = coords[2 * p1];
    sy[c1] = coords[2 * p1 + 1];
    ss[c1] = scores[p1];
  }
}

// ---------------------------------------------------------------------------
// B: brute-force higher-priority in-radius neighbor lists in rank space.
// Thread (r, chunk): scan 512 ranks q in its chunk, keep q < r within radius.
// q is wave-uniform -> sx[q]/sy[q] become scalar loads (L2-resident).
// Blocks whose whole chunk is >= their rank range exit immediately (half the
// grid), so total work ~ 33M pair tests ~ 2 us device-wide.
// sqrt(d2) < 8 <=> d2 < 64 exactly in f32 (correctly-rounded sqrt is
// monotone and 8^2=64 is exact; the boundary case rounds down) -- no sqrt.
// ---------------------------------------------------------------------------
__global__ __launch_bounds__(256) void k_nbr(const float* __restrict__ sx,
                                             const float* __restrict__ sy,
                                             u32* __restrict__ nbr_cnt,
                                             u16* __restrict__ nbr) {
  int r0 = (blockIdx.x & 31) << 8;  // rank range [r0, r0+255]
  int q0 = (blockIdx.x >> 5) << 9;  // chunk [q0, q0+511]
  if (q0 > r0 + 254) return;        // no lane has q < r
  int r = r0 + threadIdx.x;
  float x = sx[r], y = sy[r];
  int nmax = r0 + 255 - q0;
  if (nmax > 512) nmax = 512;
  for (int j = 0; j < nmax; ++j) {
    int q = q0 + j;
    float qx = sx[q], qy = sy[q];  // uniform -> s_load
    // mirror reference arithmetic: sub, mul, mul, add (no fma contraction)
    float dx = __fsub_rn(x, qx);
    float dy = __fsub_rn(y, qy);
    float d2 = __fadd_rn(__fmul_rn(dx, dx), __fmul_rn(dy, dy));
    if (q < r && d2 < 64.0f) {
      u32 sl = atomicAdd(&nbr_cnt[r], 1u);
      if (sl < CAP) nbr[(size_t)sl * NPTS + r] = (u16)q;
    }
  }
}

// ---------------------------------------------------------------------------
// C: segmented Gauss-Seidel greedy fixpoint in rank space (1 block, 1024 thr).
// Per segment of 1024 ranks: round 0 reads the global nbr lists once
// (coalesced column-major), resolves prefix suppression (prefix is final),
// caches in-segment neighbor ranks in LDS; rounds >=1 are LDS-only Jacobi
// (expected in-seg in-degree ~0.4 -> ~3-5 rounds). 4-slot rotating changed
// flag gives 1 barrier/round; all post-barrier races are 0-over-0 benign.
// ---------------------------------------------------------------------------
__global__ __launch_bounds__(1024) void k_nms(const u32* __restrict__ nbr_cnt,
                                              const u16* __restrict__ nbr,
                                              const u32* __restrict__ sorted_id,
                                              const float* __restrict__ ss,
                                              float* __restrict__ out) {
  __shared__ u8 keep[NPTS];
  __shared__ u16 ins[SEG * KMAX];
  __shared__ int slot[4];
  int t = threadIdx.x;

  for (int s = 0; s < NSEG; ++s) {
    int segbase = s << 10;
    int p = segbase + t;
    u32 cnt = nbr_cnt[p];
    if (cnt > CAP) cnt = CAP;
    const u16* row = nbr + p;  // entry n at row[n*NPTS], coalesced over t
    u32 kin = 0;
    bool supPrefix = false;
    for (u32 n = 0; n < cnt; ++n) {
      u32 q = row[(size_t)n * NPTS];
      if (q < (u32)segbase) {
        if (keep[q]) { supPrefix = true; break; }  // prefix is final
      } else {
        if (kin < KMAX) ins[t * KMAX + kin] = (u16)q;
        kin++;
      }
    }
    bool fallback = (kin > KMAX);  // rare overflow: rescan global each round
    bool active = !supPrefix && (kin > 0);
    keep[p] = supPrefix ? (u8)0 : (u8)1;
    if (t < 4) slot[t] = 0;
    __syncthreads();

    for (int r = 1; r <= SEG + 2; ++r) {
      if (t == 0) slot[(r + 2) & 3] = 0;
      bool flip = false;
      if (active) {
        bool alive = true;
        if (!fallback) {
          for (u32 n = 0; n < kin; ++n)
            if (keep[ins[t * KMAX + n]]) { alive = false; break; }
        } else {
          for (u32 n = 0; n < cnt; ++n) {
            u32 q = row[(size_t)n * NPTS];
            if (q >= (u32)segbase && keep[q]) { alive = false; break; }
          }
        }
        u8 a = alive ? (u8)1 : (u8)0;
        if (keep[p] != a) { keep[p] = a; flip = true; }
      }
      if (flip) slot[r & 3] = 1;
      __syncthreads();
      if (slot[r & 3] == 0) break;  // full Jacobi round w/o flips: fixpoint
    }
  }

  // epilogue: keep mask (original order) + suppressed scores (rank order)
  for (int k = t; k < NPTS; k += 1024) {
    u8 kp = keep[k];
    out[sorted_id[k]] = kp ? 1.0f : 0.0f;
    out[NPTS + k] = kp ? ss[k] : 0.0f;
  }
}

// ---------------------------------------------------------------------------
extern "C" void kernel_launch(void* const* d_in, const int* in_sizes, int n_in,
                              void* d_out, int out_size, void* d_ws, size_t ws_size,
                              hipStream_t stream) {
  const float* coords = (const float*)d_in[0];  // [N,2]
  const float* scores = (const float*)d_in[1];  // [N]
  float* out = (float*)d_out;                   // [N keep | N suppressed scores]

  char* ws = (char*)d_ws;
  size_t off = 0;
  u16* nbr       = (u16*)(ws + off); off += (size_t)CAP * NPTS * 2;  // 512K
  u32* sorted_id = (u32*)(ws + off); off += (size_t)NPTS * 4;        // 32K
  float* sx      = (float*)(ws + off); off += (size_t)NPTS * 4;      // 32K
  float* sy      = (float*)(ws + off); off += (size_t)NPTS * 4;      // 32K
  float* ss      = (float*)(ws + off); off += (size_t)NPTS * 4;      // 32K
  u32* nbr_cnt   = (u32*)(ws + off); off += (size_t)NPTS * 4;        // 32K

  k_rank<<<256, 256, 0, stream>>>(coords, scores, sorted_id, sx, sy, ss, nbr_cnt);
  k_nbr<<<512, 256, 0, stream>>>(sx, sy, nbr_cnt, nbr);
  k_nms<<<1, 1024, 0, stream>>>(nbr_cnt, nbr, sorted_id, ss, out);
}

// Round 5
// 182.747 us; speedup vs baseline: 4.3660x; 1.1707x over previous
//
#include <hip/hip_runtime.h>
#include <stdint.h>

typedef unsigned int u32;
typedef unsigned long long u64;
typedef unsigned short u16;
typedef unsigned char u8;

#define NPTS 8192
#define CAP 32
#define KMAX 8
#define SEG 1024
#define NSEG 8

// ---------------------------------------------------------------------------
// A: rank by counting + scatter into rank space. 256 blocks x 1024 threads
// (16 waves/CU -> real latency hiding, unlike the r4 version's 4 waves/CU).
// Block ranks 32 points; thread = (point g = t>>5, slice s = t&31 of 256
// keys). Keys cached once in LDS (32 KB). uint4 reads with +s rotation:
// 4-way bank aliasing (1.58x, acceptable), lanes t,t+32 broadcast-pair.
// Exact stable rank: #{q: key_q > key_p or (==, q < p)}.
// Block 0 also zeroes nbr_cnt -- no memset node.
// ---------------------------------------------------------------------------
__global__ __launch_bounds__(1024) void k_rank(const float* __restrict__ coords,
                                               const float* __restrict__ scores,
                                               u32* __restrict__ sorted_id,
                                               float* __restrict__ sx,
                                               float* __restrict__ sy,
                                               float* __restrict__ ss,
                                               u32* __restrict__ nbr_cnt) {
  __shared__ u32 skey[NPTS];
  int t = threadIdx.x, B = blockIdx.x;
  for (int k = t; k < NPTS; k += 1024) skey[k] = __float_as_uint(scores[k]);
  if (B == 0) {
    for (int k = t; k < NPTS; k += 1024) nbr_cnt[k] = 0;
  }
  __syncthreads();

  int s = t & 31;   // slice 0..31 (half-wave lanes), 256 keys each
  int g = t >> 5;   // point group 0..31
  int p = B * 32 + g;
  u32 kp = skey[p];
  const uint4* k4 = (const uint4*)skey;
  int b4 = s << 6;  // slice base in uint4 units
  u32 c = 0;
#pragma unroll 4
  for (int j = 0; j < 64; ++j) {
    int jj = (j + s) & 63;  // rotate so lanes spread across bank groups
    uint4 kv = k4[b4 + jj];
    int q = (s << 8) + (jj << 2);
    c += (kv.x > kp || (kv.x == kp && q + 0 < p)) ? 1u : 0u;
    c += (kv.y > kp || (kv.y == kp && q + 1 < p)) ? 1u : 0u;
    c += (kv.z > kp || (kv.z == kp && q + 2 < p)) ? 1u : 0u;
    c += (kv.w > kp || (kv.w == kp && q + 3 < p)) ? 1u : 0u;
  }
  // butterfly sum over the 32 slices (stays within each 32-lane half-wave)
  c += __shfl_xor(c, 1);
  c += __shfl_xor(c, 2);
  c += __shfl_xor(c, 4);
  c += __shfl_xor(c, 8);
  c += __shfl_xor(c, 16);
  if (s == 0) {
    sorted_id[c] = (u32)p;
    sx[c] = coords[2 * p];      // bitwise copies keep arithmetic exact
    sy[c] = coords[2 * p + 1];
    ss[c] = scores[p];
  }
}

// ---------------------------------------------------------------------------
// B: brute-force higher-priority in-radius neighbor lists in rank space.
// Block = (r-range of 256, q-chunk of 512). Chunk coords staged in LDS;
// inner loop reads LDS at uniform j -> broadcast, no bank conflicts, no
// serialized scalar global loads (the r4 mistake). ~33M pair tests ~5 us.
// sqrt(d2) < 8 <=> d2 < 64 exactly in f32 (correctly-rounded sqrt, 64
// exact) -- sqrt eliminated without changing any boundary decision.
// ---------------------------------------------------------------------------
__global__ __launch_bounds__(256) void k_nbr(const float* __restrict__ sx,
                                             const float* __restrict__ sy,
                                             u32* __restrict__ nbr_cnt,
                                             u16* __restrict__ nbr) {
  __shared__ float qx[512], qy[512];
  int r0 = (int)(blockIdx.x & 31) << 8;  // rank range [r0, r0+255]
  int q0 = (int)(blockIdx.x >> 5) << 9;  // chunk [q0, q0+511]
  if (q0 > r0 + 254) return;             // block-uniform: no lane has q < r
  int t = threadIdx.x;
  for (int k = t; k < 512; k += 256) {   // coalesced stage (always in-bounds)
    qx[k] = sx[q0 + k];
    qy[k] = sy[q0 + k];
  }
  __syncthreads();

  int r = r0 + t;
  float x = sx[r], y = sy[r];
  int nmax = r0 + 255 - q0;  // largest useful j is r0+254-q0
  if (nmax > 512) nmax = 512;
  for (int j = 0; j < nmax; ++j) {
    // mirror reference arithmetic: sub, mul, mul, add (no fma contraction)
    float dx = __fsub_rn(x, qx[j]);
    float dy = __fsub_rn(y, qy[j]);
    float d2 = __fadd_rn(__fmul_rn(dx, dx), __fmul_rn(dy, dy));
    int q = q0 + j;
    if (d2 < 64.0f && q < r) {
      u32 sl = atomicAdd(&nbr_cnt[r], 1u);
      if (sl < CAP) nbr[(size_t)sl * NPTS + r] = (u16)q;
    }
  }
}

// ---------------------------------------------------------------------------
// C: segmented Gauss-Seidel greedy fixpoint in rank space (1 block, 1024 thr).
// Per 1024-rank segment: round 0 reads the global nbr lists once (coalesced,
// break-free so loads pipeline), resolves prefix suppression (prefix final),
// caches in-segment neighbor ranks in LDS; rounds >=1 are LDS-only Jacobi
// (in-seg in-degree ~0.4 -> ~2-4 rounds). 4-slot rotating changed flag gives
// 1 barrier/round; post-barrier races are 0-over-0 benign.
// ---------------------------------------------------------------------------
__global__ __launch_bounds__(1024) void k_nms(const u32* __restrict__ nbr_cnt,
                                              const u16* __restrict__ nbr,
                                              const u32* __restrict__ sorted_id,
                                              const float* __restrict__ ss,
                                              float* __restrict__ out) {
  __shared__ u8 keep[NPTS];
  __shared__ u16 ins[SEG * KMAX];
  __shared__ int slot[4];
  int t = threadIdx.x;

  for (int s = 0; s < NSEG; ++s) {
    int segbase = s << 10;
    int p = segbase + t;
    u32 cnt = nbr_cnt[p];
    if (cnt > CAP) cnt = CAP;
    const u16* row = nbr + p;  // entry n at row[n*NPTS], coalesced over t
    u32 kin = 0;
    bool supPrefix = false;
    for (u32 n = 0; n < cnt; ++n) {  // break-free: global loads pipeline
      u32 q = row[(size_t)n * NPTS];
      if (q < (u32)segbase) {
        if (keep[q]) supPrefix = true;  // prefix segments are final
      } else {
        if (kin < KMAX) ins[t * KMAX + kin] = (u16)q;
        kin++;
      }
    }
    bool fallback = (kin > KMAX);  // rare overflow: rescan global each round
    bool active = !supPrefix && (kin > 0);
    keep[p] = supPrefix ? (u8)0 : (u8)1;
    if (t < 4) slot[t] = 0;
    __syncthreads();

    for (int r = 1; r <= SEG + 2; ++r) {
      if (t == 0) slot[(r + 2) & 3] = 0;
      bool flip = false;
      if (active) {
        bool alive = true;
        if (!fallback) {
          for (u32 n = 0; n < kin; ++n)
            if (keep[ins[t * KMAX + n]]) { alive = false; break; }
        } else {
          for (u32 n = 0; n < cnt; ++n) {
            u32 q = row[(size_t)n * NPTS];
            if (q >= (u32)segbase && keep[q]) { alive = false; break; }
          }
        }
        u8 a = alive ? (u8)1 : (u8)0;
        if (keep[p] != a) { keep[p] = a; flip = true; }
      }
      if (flip) slot[r & 3] = 1;
      __syncthreads();
      if (slot[r & 3] == 0) break;  // full Jacobi round w/o flips: fixpoint
    }
  }

  // epilogue: keep mask (original order) + suppressed scores (rank order)
  for (int k = t; k < NPTS; k += 1024) {
    u8 kp = keep[k];
    out[sorted_id[k]] = kp ? 1.0f : 0.0f;
    out[NPTS + k] = kp ? ss[k] : 0.0f;
  }
}

// ---------------------------------------------------------------------------
extern "C" void kernel_launch(void* const* d_in, const int* in_sizes, int n_in,
                              void* d_out, int out_size, void* d_ws, size_t ws_size,
                              hipStream_t stream) {
  const float* coords = (const float*)d_in[0];  // [N,2]
  const float* scores = (const float*)d_in[1];  // [N]
  float* out = (float*)d_out;                   // [N keep | N suppressed scores]

  char* ws = (char*)d_ws;
  size_t off = 0;
  u16* nbr       = (u16*)(ws + off); off += (size_t)CAP * NPTS * 2;  // 512K
  u32* sorted_id = (u32*)(ws + off); off += (size_t)NPTS * 4;        // 32K
  float* sx      = (float*)(ws + off); off += (size_t)NPTS * 4;      // 32K
  float* sy      = (float*)(ws + off); off += (size_t)NPTS * 4;      // 32K
  float* ss      = (float*)(ws + off); off += (size_t)NPTS * 4;      // 32K
  u32* nbr_cnt   = (u32*)(ws + off); off += (size_t)NPTS * 4;        // 32K

  k_rank<<<256, 1024, 0, stream>>>(coords, scores, sorted_id, sx, sy, ss, nbr_cnt);
  k_nbr<<<512, 256, 0, stream>>>(sx, sy, nbr_cnt, nbr);
  k_nms<<<1, 1024, 0, stream>>>(nbr_cnt, nbr, sorted_id, ss, out);
}

// Round 6
// 129.767 us; speedup vs baseline: 6.1485x; 1.4083x over previous
//
#include <hip/hip_runtime.h>
#include <stdint.h>

typedef unsigned int u32;
typedef unsigned long long u64;
typedef unsigned short u16;
typedef unsigned char u8;

#define NPTS 8192
#define CAP 32
#define KMAX 8
#define SEG 1024
#define NSEG 8

// ---------------------------------------------------------------------------
// A: rank by counting + scatter into rank space. 256 blocks x 1024 threads.
// (unchanged from round 5 -- it left the top-5 there)
// ---------------------------------------------------------------------------
__global__ __launch_bounds__(1024) void k_rank(const float* __restrict__ coords,
                                               const float* __restrict__ scores,
                                               u32* __restrict__ sorted_id,
                                               float* __restrict__ sx,
                                               float* __restrict__ sy,
                                               float* __restrict__ ss,
                                               u32* __restrict__ nbr_cnt) {
  __shared__ u32 skey[NPTS];
  int t = threadIdx.x, B = blockIdx.x;
  for (int k = t; k < NPTS; k += 1024) skey[k] = __float_as_uint(scores[k]);
  if (B == 0) {
    for (int k = t; k < NPTS; k += 1024) nbr_cnt[k] = 0;
  }
  __syncthreads();

  int s = t & 31;   // slice 0..31, 256 keys each
  int g = t >> 5;   // point group 0..31
  int p = B * 32 + g;
  u32 kp = skey[p];
  const uint4* k4 = (const uint4*)skey;
  int b4 = s << 6;
  u32 c = 0;
#pragma unroll 4
  for (int j = 0; j < 64; ++j) {
    int jj = (j + s) & 63;  // rotate across bank groups (4-way alias, 1.58x)
    uint4 kv = k4[b4 + jj];
    int q = (s << 8) + (jj << 2);
    c += (kv.x > kp || (kv.x == kp && q + 0 < p)) ? 1u : 0u;
    c += (kv.y > kp || (kv.y == kp && q + 1 < p)) ? 1u : 0u;
    c += (kv.z > kp || (kv.z == kp && q + 2 < p)) ? 1u : 0u;
    c += (kv.w > kp || (kv.w == kp && q + 3 < p)) ? 1u : 0u;
  }
  c += __shfl_xor(c, 1);
  c += __shfl_xor(c, 2);
  c += __shfl_xor(c, 4);
  c += __shfl_xor(c, 8);
  c += __shfl_xor(c, 16);
  if (s == 0) {
    sorted_id[c] = (u32)p;
    sx[c] = coords[2 * p];      // bitwise copies keep arithmetic exact
    sy[c] = coords[2 * p + 1];
    ss[c] = scores[p];
  }
}

// ---------------------------------------------------------------------------
// B: higher-priority in-radius neighbor lists, rank space, brute force.
// Triangular grid of ONLY-working tiles: tile = (R: 256 ranks, C: 128 q's),
// working iff C <= 2R+1 -> 32*33 = 1056 blocks (~4/CU, uniform work, no
// early-exit starvation like r5). Inner loop is ATOMIC-FREE: per 32-q group
// build a predicate bitmask from float4 LDS broadcast reads (fully
// unrolled, pipelines), then ctz-extract the rare hits (lambda~3/point)
// with atomics. q<r hoisted to a per-group mask (nontrivial only for the
// 2 diagonal chunks per R). d2 < 64 <=> sqrt(d2) < 8 exactly in f32.
// ---------------------------------------------------------------------------
__global__ __launch_bounds__(256) void k_nbr(const float* __restrict__ sx,
                                             const float* __restrict__ sy,
                                             u32* __restrict__ nbr_cnt,
                                             u16* __restrict__ nbr) {
  __shared__ float qx[128], qy[128];
  int b = blockIdx.x;
  // triangular decode: R = max{k : k(k+1) <= b}, C = b - R(R+1) in [0, 2R+1]
  int R = (int)((__fsqrt_rn(4.0f * (float)b + 1.0f) - 1.0f) * 0.5f);
  while ((R + 1) * (R + 2) <= b) ++R;
  while (R * (R + 1) > b) --R;
  int C = b - R * (R + 1);
  int t = threadIdx.x;
  int q0 = C << 7;
  int r = (R << 8) + t;
  if (t < 128) qx[t] = sx[q0 + t];
  else         qy[t - 128] = sy[q0 + t - 128];
  __syncthreads();

  float x = sx[r], y = sy[r];
  // jlim = #valid j (q0+j < r). dC = C-2R <= 1; only diagonal chunks clip.
  int jlim = 128;
  int dC = C - 2 * R;
  if (dC >= 0) {
    jlim = t - (dC << 7);
    if (jlim < 0) jlim = 0;
    if (jlim > 128) jlim = 128;
  }
  const float4* x4 = (const float4*)qx;
  const float4* y4 = (const float4*)qy;
  for (int jg = 0; jg < 4; ++jg) {
    int base = jg << 5;
    int v = jlim - base;
    u32 gm = (v >= 32) ? 0xFFFFFFFFu : ((v <= 0) ? 0u : ((1u << v) - 1u));
    u32 m = 0;
#pragma unroll
    for (int j4 = 0; j4 < 8; ++j4) {
      float4 xv = x4[(base >> 2) + j4];  // uniform addr -> LDS broadcast
      float4 yv = y4[(base >> 2) + j4];
      // mirror reference arithmetic: sub, mul, mul, add (no fma contraction)
      float dx0 = __fsub_rn(x, xv.x), dy0 = __fsub_rn(y, yv.x);
      float dx1 = __fsub_rn(x, xv.y), dy1 = __fsub_rn(y, yv.y);
      float dx2 = __fsub_rn(x, xv.z), dy2 = __fsub_rn(y, yv.z);
      float dx3 = __fsub_rn(x, xv.w), dy3 = __fsub_rn(y, yv.w);
      if (__fadd_rn(__fmul_rn(dx0, dx0), __fmul_rn(dy0, dy0)) < 64.0f) m |= 1u << (4 * j4 + 0);
      if (__fadd_rn(__fmul_rn(dx1, dx1), __fmul_rn(dy1, dy1)) < 64.0f) m |= 1u << (4 * j4 + 1);
      if (__fadd_rn(__fmul_rn(dx2, dx2), __fmul_rn(dy2, dy2)) < 64.0f) m |= 1u << (4 * j4 + 2);
      if (__fadd_rn(__fmul_rn(dx3, dx3), __fmul_rn(dy3, dy3)) < 64.0f) m |= 1u << (4 * j4 + 3);
    }
    m &= gm;
    while (m) {  // rare: expected ~0.4 bits per thread over all 4 groups
      int j2 = __builtin_ctz(m);
      m &= m - 1;
      u32 sl = atomicAdd(&nbr_cnt[r], 1u);
      if (sl < CAP) nbr[(size_t)sl * NPTS + r] = (u16)(q0 + base + j2);
    }
  }
}

// ---------------------------------------------------------------------------
// C: segmented Gauss-Seidel greedy fixpoint (1 block, 1024 thr). Round 0 of
// each segment consumes PREFETCHED (issued one segment early) nbr_cnt + the
// first 6 list rows -> global latency hidden behind the previous segment's
// Jacobi rounds. Rounds >=1 are LDS-only (in-seg in-degree ~0.4).
// 4-slot rotating changed flag: 1 barrier/round, races are 0-over-0 benign.
// ---------------------------------------------------------------------------
__global__ __launch_bounds__(1024) void k_nms(const u32* __restrict__ nbr_cnt,
                                              const u16* __restrict__ nbr,
                                              const u32* __restrict__ sorted_id,
                                              const float* __restrict__ ss,
                                              float* __restrict__ out) {
  __shared__ u8 keep[NPTS];
  __shared__ u16 ins[SEG * KMAX];
  __shared__ int slot[4];
  int t = threadIdx.x;

  // prefetch segment 0
  u32 cnt_n = nbr_cnt[t];
  u16 e0n = nbr[t];
  u16 e1n = nbr[1 * NPTS + t];
  u16 e2n = nbr[2 * NPTS + t];
  u16 e3n = nbr[3 * NPTS + t];
  u16 e4n = nbr[4 * NPTS + t];
  u16 e5n = nbr[5 * NPTS + t];

  for (int s = 0; s < NSEG; ++s) {
    int segbase = s << 10;
    int p = segbase + t;
    u32 cnt = cnt_n; if (cnt > CAP) cnt = CAP;
    u16 e0 = e0n, e1 = e1n, e2 = e2n, e3 = e3n, e4 = e4n, e5 = e5n;
    const u16* row = nbr + p;  // entry n at row[n*NPTS]
    if (s + 1 < NSEG) {        // issue next segment's loads NOW
      int pn = p + SEG;
      cnt_n = nbr_cnt[pn];
      e0n = nbr[pn];
      e1n = nbr[1 * NPTS + pn];
      e2n = nbr[2 * NPTS + pn];
      e3n = nbr[3 * NPTS + pn];
      e4n = nbr[4 * NPTS + pn];
      e5n = nbr[5 * NPTS + pn];
    }

    u32 kin = 0;
    bool supPrefix = false;
#define PROC(E) { u32 qq = (E); \
    if (qq < (u32)segbase) { supPrefix |= (keep[qq] != 0); } \
    else { if (kin < KMAX) ins[t * KMAX + kin] = (u16)qq; kin++; } }
    if (cnt > 0) PROC(e0)
    if (cnt > 1) PROC(e1)
    if (cnt > 2) PROC(e2)
    if (cnt > 3) PROC(e3)
    if (cnt > 4) PROC(e4)
    if (cnt > 5) PROC(e5)
    for (u32 n = 6; n < cnt; ++n) PROC(row[(size_t)n * NPTS])
#undef PROC
    bool fallback = (kin > KMAX);  // rare overflow: rescan global each round
    bool active = !supPrefix && (kin > 0);
    keep[p] = supPrefix ? (u8)0 : (u8)1;
    if (t < 4) slot[t] = 0;
    __syncthreads();

    for (int r = 1; r <= SEG + 2; ++r) {
      if (t == 0) slot[(r + 2) & 3] = 0;
      bool flip = false;
      if (active) {
        bool alive = true;
        if (!fallback) {
          for (u32 n = 0; n < kin; ++n)
            if (keep[ins[t * KMAX + n]]) { alive = false; break; }
        } else {
          for (u32 n = 0; n < cnt; ++n) {
            u32 q = row[(size_t)n * NPTS];
            if (q >= (u32)segbase && keep[q]) { alive = false; break; }
          }
        }
        u8 a = alive ? (u8)1 : (u8)0;
        if (keep[p] != a) { keep[p] = a; flip = true; }
      }
      if (flip) slot[r & 3] = 1;
      __syncthreads();
      if (slot[r & 3] == 0) break;  // full Jacobi round w/o flips: fixpoint
    }
  }

  // epilogue: keep mask (original order) + suppressed scores (rank order)
  for (int k = t; k < NPTS; k += 1024) {
    u8 kp = keep[k];
    out[sorted_id[k]] = kp ? 1.0f : 0.0f;
    out[NPTS + k] = kp ? ss[k] : 0.0f;
  }
}

// ---------------------------------------------------------------------------
extern "C" void kernel_launch(void* const* d_in, const int* in_sizes, int n_in,
                              void* d_out, int out_size, void* d_ws, size_t ws_size,
                              hipStream_t stream) {
  const float* coords = (const float*)d_in[0];  // [N,2]
  const float* scores = (const float*)d_in[1];  // [N]
  float* out = (float*)d_out;                   // [N keep | N suppressed scores]

  char* ws = (char*)d_ws;
  size_t off = 0;
  u16* nbr       = (u16*)(ws + off); off += (size_t)CAP * NPTS * 2;  // 512K
  u32* sorted_id = (u32*)(ws + off); off += (size_t)NPTS * 4;        // 32K
  float* sx      = (float*)(ws + off); off += (size_t)NPTS * 4;      // 32K
  float* sy      = (float*)(ws + off); off += (size_t)NPTS * 4;      // 32K
  float* ss      = (float*)(ws + off); off += (size_t)NPTS * 4;      // 32K
  u32* nbr_cnt   = (u32*)(ws + off); off += (size_t)NPTS * 4;        // 32K

  k_rank<<<256, 1024, 0, stream>>>(coords, scores, sorted_id, sx, sy, ss, nbr_cnt);
  k_nbr<<<32 * 33, 256, 0, stream>>>(sx, sy, nbr_cnt, nbr);
  k_nms<<<1, 1024, 0, stream>>>(nbr_cnt, nbr, sorted_id, ss, out);
}